// Round 8
// baseline (82.742 us; speedup 1.0000x reference)
//
#include <hip/hip_runtime.h>

// N-body all-pairs gravitational force, N=8192, fp32.
//
// Round-8: packed fp32 math. r5 counter calibration showed VALU-issue time
// == 13.7us model floor; r4/r6/r7 all plateau at ~28us kernel regardless of
// TLP/ILP mix => issue-slot-bound + fixed stall fraction. Only lever left:
// fewer issue slots/pair. gfx950 v_pk_{fma,add,mul}_f32 packs 2 fp32 ops
// per slot. Pack across 2 i-bodies (ext_vector_type(2) + elementwise_fma):
// 12 pk + 2 rsq per 2 pairs = ~20 cyc/pair vs 32 -> floor ~8.6us.
//  - BLOCK=128, IBLK=4 (2 packed groups), grid (16,128)=2048 blocks
//    = 4 waves/SIMD; JPER=64 -> 1KB LDS tile, ONE barrier.
//  - partial stores [128][N*3] (12.6MB) + reduce pass; no atomics.

typedef float v2f __attribute__((ext_vector_type(2)));

constexpr int   NBODY   = 8192;
constexpr int   BLOCK   = 128;
constexpr int   IBLK    = 4;                   // bodies/thread = 2 packed groups
constexpr int   GRP     = IBLK / 2;            // 2
constexpr int   IBODIES = BLOCK * IBLK;        // 512 i's per block
constexpr int   JSPLIT  = 128;
constexpr int   JPER    = NBODY / JSPLIT;      // 64 j's per block
constexpr float SOFT2   = 0.01f * 0.01f;
constexpr int   OUTE    = NBODY * 3;           // 24576

__global__ __launch_bounds__(BLOCK, 4) void nbody_forces(
    const float* __restrict__ pos,       // [N,3]
    const float* __restrict__ mass,      // [N]
    float*       __restrict__ part)      // [JSPLIT][N*3] partials
{
    const int tid   = threadIdx.x;
    const int iBase = blockIdx.x * IBODIES + tid;
    const int j0    = blockIdx.y * JPER;

    __shared__ float4 sh[JPER];
    if (tid < JPER) {
        const int j = j0 + tid;
        sh[tid] = make_float4(pos[3 * j + 0], pos[3 * j + 1], pos[3 * j + 2], mass[j]);
    }

    v2f px[GRP], py[GRP], pz[GRP];
    #pragma unroll
    for (int g = 0; g < GRP; ++g) {
        const int i0 = iBase + (2 * g + 0) * BLOCK;
        const int i1 = iBase + (2 * g + 1) * BLOCK;
        px[g] = (v2f){pos[3 * i0 + 0], pos[3 * i1 + 0]};
        py[g] = (v2f){pos[3 * i0 + 1], pos[3 * i1 + 1]};
        pz[g] = (v2f){pos[3 * i0 + 2], pos[3 * i1 + 2]};
    }
    __syncthreads();

    v2f fx[GRP], fy[GRP], fz[GRP];
    #pragma unroll
    for (int g = 0; g < GRP; ++g) {
        fx[g] = (v2f){0.f, 0.f}; fy[g] = (v2f){0.f, 0.f}; fz[g] = (v2f){0.f, 0.f};
    }

    const v2f soft2 = (v2f){SOFT2, SOFT2};

    #pragma unroll 4
    for (int k = 0; k < JPER; ++k) {
        const float4 p = sh[k];            // uniform addr -> HW broadcast
        const v2f jx = (v2f){p.x, p.x};
        const v2f jy = (v2f){p.y, p.y};
        const v2f jz = (v2f){p.z, p.z};
        const v2f jm = (v2f){p.w, p.w};
        #pragma unroll
        for (int g = 0; g < GRP; ++g) {    // each group = 2 bodies, pk ops
            const v2f dx = jx - px[g];                       // v_pk_add (neg)
            const v2f dy = jy - py[g];
            const v2f dz = jz - pz[g];
            v2f d2 = __builtin_elementwise_fma(dz, dz, soft2);
            d2     = __builtin_elementwise_fma(dy, dy, d2);
            d2     = __builtin_elementwise_fma(dx, dx, d2);  // 3x v_pk_fma
            v2f inv;
            inv.x = __builtin_amdgcn_rsqf(d2.x);             // v_rsq_f32
            inv.y = __builtin_amdgcn_rsqf(d2.y);
            const v2f inv2 = inv * inv;                      // v_pk_mul
            const v2f inv3 = inv2 * inv;
            const v2f s    = inv3 * jm;
            fx[g] = __builtin_elementwise_fma(s, dx, fx[g]); // 3x v_pk_fma
            fy[g] = __builtin_elementwise_fma(s, dy, fy[g]);
            fz[g] = __builtin_elementwise_fma(s, dz, fz[g]);
            // j == i: diff = 0 -> contribution 0, matches reference.
        }
    }

    float* dst = part + (size_t)blockIdx.y * OUTE;
    #pragma unroll
    for (int g = 0; g < GRP; ++g) {
        #pragma unroll
        for (int h = 0; h < 2; ++h) {
            const int i = iBase + (2 * g + h) * BLOCK;
            dst[3 * i + 0] = fx[g][h];
            dst[3 * i + 1] = fy[g][h];
            dst[3 * i + 2] = fz[g][h];
        }
    }
}

__global__ __launch_bounds__(256) void reduce_kernel(
    const float* __restrict__ part,      // [JSPLIT][OUTE]
    float*       __restrict__ out)       // [OUTE]
{
    const int e = blockIdx.x * blockDim.x + threadIdx.x;   // 0..OUTE-1
    float s = 0.f;
    #pragma unroll 8
    for (int k = 0; k < JSPLIT; ++k)
        s += part[(size_t)k * OUTE + e];
    out[e] = s;
}

extern "C" void kernel_launch(void* const* d_in, const int* in_sizes, int n_in,
                              void* d_out, int out_size, void* d_ws, size_t ws_size,
                              hipStream_t stream) {
    const float* pos  = (const float*)d_in[0];
    const float* mass = (const float*)d_in[1];
    float* out = (float*)d_out;

    float* part = (float*)d_ws;          // [JSPLIT][OUTE] = 12.6 MB

    dim3 grid(NBODY / IBODIES, JSPLIT);  // (16, 128) = 2048 blocks
    nbody_forces<<<grid, BLOCK, 0, stream>>>(pos, mass, part);

    reduce_kernel<<<OUTE / 256, 256, 0, stream>>>(part, out);
}